// Round 14
// baseline (90.800 us; speedup 1.0000x reference)
//
#include <hip/hip_runtime.h>
#include <hip/hip_bf16.h>

// SelfAttention b=2, heads=8, D=32, n=4096 (64x64).
// Pass 1 (proj_kernel, z=Q/K/V): x -> Q bf16 [bg][n][32] (pre-scaled by
//   SCALE*log2e), K2 bf16 [bg][dgrp=d/8][key][8], V2 bf16
//   [bg][keygrp=key/8][d][8] -- fragment-native layouts (r13-proven: every
//   in-loop MFMA operand load is a 1KB-contiguous wave load).
// Pass 2 (attn_kernel): 32x32 MFMA flash attention, 32 q/wave, KVBLK=32,
//   no LDS in the loop (r12-proven). KEY-SPLIT (r14): block = 4 waves,
//   64 q; wave (qhalf,khalf) does q-subtile qhalf over key-half khalf ->
//   4096 waves -> 4 waves/SIMD (r13 showed VALU idle 1/3 at 2 waves/SIMD).
//   Endgame: khalf=1 writes fp32 oacc+lacc to LDS, one __syncthreads,
//   khalf=0 merges then normalize + Wp epilogue (r13-proven).
//   Loop body: S^T = mfma32(K,Q)x2 (col=q=lane&31), exp2 x16 ->
//   cvt_pk x8 -> v_permlane32_swap_b32 x4 -> PV A-frags -> mfma32(P,V)x2.

constexpr int D = 32;
constexpr int N = 4096;
constexpr int NBG = 16;
constexpr float SCALE = 0.17677669529663687f;   // 32^-0.5
constexpr float LOG2E = 1.4426950408889634f;

using bfrag  = __attribute__((ext_vector_type(8))) short;   // 8 bf16
using s16x8  = __attribute__((ext_vector_type(8))) short;
using f32x16 = __attribute__((ext_vector_type(16))) float;
typedef unsigned short u16;
typedef unsigned int u32;

constexpr int PSTR = 34;            // endgame tile row stride in u16

__device__ __forceinline__ float fexp2(float x) { return __builtin_amdgcn_exp2f(x); }

__device__ __forceinline__ short f2bfs(float f) {
    __hip_bfloat16 h = __float2bfloat16(f);
    return (short)__builtin_bit_cast(u16, h);
}

__device__ __forceinline__ u32 cvt_pk_bf16(float lo, float hi) {
    u32 r;
    asm("v_cvt_pk_bf16_f32 %0, %1, %2" : "=v"(r) : "v"(lo), "v"(hi));
    return r;
}

// swap lanes 32-63 of a with lanes 0-31 of b (in place)
__device__ __forceinline__ void permswap(u32& a, u32& b) {
    asm("v_permlane32_swap_b32 %0, %1" : "+v"(a), "+v"(b));
}

// ---------------- pass 1: projections -> fragment-native bf16 scratch -----
__global__ __launch_bounds__(256) void proj_kernel(
    const float* __restrict__ x,
    const float* __restrict__ Wq, const float* __restrict__ bq,
    const float* __restrict__ Wk, const float* __restrict__ bk,
    const float* __restrict__ Wv, const float* __restrict__ bv,
    u16* __restrict__ Qb, u16* __restrict__ K2, u16* __restrict__ V2) {
    const int bg = blockIdx.y, g = bg & 7;
    const int z  = blockIdx.z;                       // 0=Q 1=K 2=V
    const int i  = blockIdx.x * 256 + threadIdx.x;   // key / pixel index

    const float* W  = (z == 0) ? Wq : (z == 1) ? Wk : Wv;
    const float* bb = (z == 0) ? bq : (z == 1) ? bk : bv;

    const float* xb = x + (size_t)bg * D * N;
    float xv[D];
#pragma unroll
    for (int d = 0; d < D; ++d) xv[d] = xb[(size_t)d * N + i];

    const float* w = W + g * D * D;
    float acc[D];
#pragma unroll
    for (int o = 0; o < D; ++o) {
        float a0 = 0.f, a1 = 0.f, a2 = 0.f, a3 = 0.f;
#pragma unroll
        for (int d = 0; d < D; d += 4) {
            a0 = fmaf(w[o * D + d    ], xv[d    ], a0);
            a1 = fmaf(w[o * D + d + 1], xv[d + 1], a1);
            a2 = fmaf(w[o * D + d + 2], xv[d + 2], a2);
            a3 = fmaf(w[o * D + d + 3], xv[d + 3], a3);
        }
        acc[o] = (a0 + a1) + (a2 + a3) + bb[g * D + o];
    }

    if (z == 0) {                                    // Q -> row [n][32]
        u16* dst = Qb + ((size_t)bg * N + i) * D;
#pragma unroll
        for (int t = 0; t < 4; ++t) {
            s16x8 v;
#pragma unroll
            for (int e = 0; e < 8; ++e) v[e] = f2bfs(acc[8 * t + e] * (SCALE * LOG2E));
            *reinterpret_cast<s16x8*>(dst + 8 * t) = v;
        }
    } else if (z == 1) {                             // K -> [dgrp][key][8]
        u16* kb2 = K2 + (size_t)bg * N * D;
#pragma unroll
        for (int t = 0; t < 4; ++t) {                // dgrp = t
            s16x8 v;
#pragma unroll
            for (int e = 0; e < 8; ++e) v[e] = f2bfs(acc[8 * t + e]);
            *reinterpret_cast<s16x8*>(kb2 + (size_t)t * N * 8 + (size_t)i * 8) = v;
        }
    } else {                                         // V -> [keygrp][d][8]
        u16* vb2 = V2 + (size_t)bg * N * D + (size_t)(i >> 3) * 256 + (i & 7);
#pragma unroll
        for (int o = 0; o < D; ++o)
            vb2[o * 8] = (u16)f2bfs(acc[o]);
    }
}

// ---------------- pass 2: 32x32 MFMA flash attention, key-split -----------
__global__ __launch_bounds__(256) void attn_kernel(
    const u16* __restrict__ Qb, const u16* __restrict__ K2, const u16* __restrict__ V2,
    const float* __restrict__ Wp, const float* __restrict__ bp,
    float* __restrict__ out) {
    const int s = blockIdx.x;
    const int bg = s & 15, qt = s >> 4, g = bg & 7;   // bg fastest -> XCD L2 reuse
    const int wid = threadIdx.x >> 6;
    const int qhalf = wid >> 1, khalf = wid & 1;
    const int lane = threadIdx.x & 63;
    const int l31 = lane & 31, h = lane >> 5;
    const int qbase = qt * 64 + qhalf * 32;           // 32 q rows per wave

    __shared__ float macc[2][17][64];                 // khalf-merge: 16 oacc + lacc
    __shared__ u16 plds_all[2][32][PSTR];             // endgame transpose (qhalf)
    u16* tile = &plds_all[qhalf][0][0];

    const u16* Qw = Qb + (size_t)bg * N * D;
    const u16* Kw = K2 + (size_t)bg * N * D;
    const u16* Vw = V2 + (size_t)bg * N * D;

    // Q B-fragments (col=q=l31, k-slots d=8h+e), held whole loop
    const u16* qrow = Qw + (size_t)(qbase + l31) * D + 8 * h;
    bfrag qf0 = *reinterpret_cast<const bfrag*>(qrow);
    bfrag qf1 = *reinterpret_cast<const bfrag*>(qrow + 16);

    // Wp B-fragments (col=o=l31, k-slots d=8h+e) + bias
    bfrag wf0, wf1;
    {
        const float* wrow = Wp + (size_t)(g * D + l31) * D + 8 * h;
#pragma unroll
        for (int e = 0; e < 8; ++e) { wf0[e] = f2bfs(wrow[e]); wf1[e] = f2bfs(wrow[16 + e]); }
    }
    const float bias = bp[g * D + l31];

    f32x16 oacc = {};
    float lacc = 0.f;

    // fragment-native bases: every in-loop load is 1KB contiguous per wave
    const u16* kBase = Kw + (size_t)h * N * 8 + (size_t)l31 * 8;  // dgrp h, key l31
    const u16* vBase = Vw + h * 256 + l31 * 8;                    // keygrp h, d=l31

    const int kb0 = khalf * (N / 2), kb1 = kb0 + N / 2;           // key half

    bfrag klo = *reinterpret_cast<const bfrag*>(kBase + (size_t)kb0 * 8);
    bfrag khi = *reinterpret_cast<const bfrag*>(kBase + 2 * N * 8 + (size_t)kb0 * 8);
    bfrag va  = *reinterpret_cast<const bfrag*>(vBase + (size_t)kb0 * 32);
    bfrag vb  = *reinterpret_cast<const bfrag*>(vBase + 512 + (size_t)kb0 * 32);

    for (int kb = kb0; kb < kb1; kb += 32) {
        bfrag kloc = klo, khic = khi, vac = va, vbc = vb;
        if (kb + 32 < kb1) {                           // register prefetch
            klo = *reinterpret_cast<const bfrag*>(kBase + (size_t)(kb + 32) * 8);
            khi = *reinterpret_cast<const bfrag*>(kBase + 2 * N * 8 + (size_t)(kb + 32) * 8);
            va  = *reinterpret_cast<const bfrag*>(vBase + (size_t)(kb + 32) * 32);
            vb  = *reinterpret_cast<const bfrag*>(vBase + 512 + (size_t)(kb + 32) * 32);
        }

        // S^T[key][q]: col=q=l31, row=key=(r&3)+8*(r>>2)+4h
        f32x16 sacc = {};
        sacc = __builtin_amdgcn_mfma_f32_32x32x16_bf16(kloc, qf0, sacc, 0, 0, 0);
        sacc = __builtin_amdgcn_mfma_f32_32x32x16_bf16(khic, qf1, sacc, 0, 0, 0);

        // exp2 (logits bounded; Q pre-scaled by log2e)
        float p[16];
#pragma unroll
        for (int r = 0; r < 16; ++r) p[r] = fexp2(sacc[r]);
        lacc += (((p[0] + p[1]) + (p[2] + p[3])) + ((p[4] + p[5]) + (p[6] + p[7])))
              + (((p[8] + p[9]) + (p[10] + p[11])) + ((p[12] + p[13]) + (p[14] + p[15])));

        // pack to bf16 pairs
        u32 u0 = cvt_pk_bf16(p[0],  p[1]),  u1 = cvt_pk_bf16(p[2],  p[3]);
        u32 u2 = cvt_pk_bf16(p[4],  p[5]),  u3 = cvt_pk_bf16(p[6],  p[7]);
        u32 u4 = cvt_pk_bf16(p[8],  p[9]),  u5 = cvt_pk_bf16(p[10], p[11]);
        u32 u6 = cvt_pk_bf16(p[12], p[13]), u7 = cvt_pk_bf16(p[14], p[15]);

        // redistribute halves: after swaps,
        //   frag1 = {u0,u1,u2,u3} = P[q=l31][keys kb+8h+e]
        //   frag2 = {u4,u5,u6,u7} = P[q=l31][keys kb+16+8h+e]
        permswap(u0, u2); permswap(u1, u3);
        permswap(u4, u6); permswap(u5, u7);
        uint4 f1 = make_uint4(u0, u1, u2, u3);
        uint4 f2 = make_uint4(u4, u5, u6, u7);

        oacc = __builtin_amdgcn_mfma_f32_32x32x16_bf16(__builtin_bit_cast(bfrag, f1), vac, oacc, 0, 0, 0);
        oacc = __builtin_amdgcn_mfma_f32_32x32x16_bf16(__builtin_bit_cast(bfrag, f2), vbc, oacc, 0, 0, 0);
    }

    // ---- merge the two key-half waves of each q pair ----
    if (khalf == 1) {
#pragma unroll
        for (int r = 0; r < 16; ++r) macc[qhalf][r][lane] = oacc[r];
        macc[qhalf][16][lane] = lacc;
    }
    __syncthreads();
    if (khalf == 1) return;
#pragma unroll
    for (int r = 0; r < 16; ++r) oacc[r] += macc[qhalf][r][lane];
    lacc += macc[qhalf][16][lane];

    // denominator for q=l31 (h halves hold the two key-subset partials)
    const float lsum = lacc + __shfl_xor(lacc, 32);
    const float linv = 1.0f / lsum;

    // normalize rows (row q of oacc reg r is (r&3)+8*(r>>2)+4h) and
    // transpose O via the endgame LDS tile: tile[q][d]
#pragma unroll
    for (int r = 0; r < 16; ++r) {
        const int q = (r & 3) + 8 * (r >> 2) + 4 * h;
        const float ir = __shfl(linv, q);
        tile[q * PSTR + l31] = (u16)f2bfs(oacc[r] * ir);
    }

    asm volatile("" ::: "memory");   // endgame only: order tile write->read

    // O A-fragments: row=q=l31, k-slots d=8h+e
    bfrag oa0 = *reinterpret_cast<const bfrag*>(tile + l31 * PSTR + 8 * h);
    bfrag oa1 = *reinterpret_cast<const bfrag*>(tile + l31 * PSTR + 16 + 8 * h);

    // OUT[q][o] = O_norm @ Wp^T + bias: col=o=l31, row=q=(r&3)+8*(r>>2)+4h
    f32x16 oc;
#pragma unroll
    for (int r = 0; r < 16; ++r) oc[r] = bias;
    oc = __builtin_amdgcn_mfma_f32_32x32x16_bf16(oa0, wf0, oc, 0, 0, 0);
    oc = __builtin_amdgcn_mfma_f32_32x32x16_bf16(oa1, wf1, oc, 0, 0, 0);

    // store: reg group rr holds q = qbase + 8*rr + 4h + {0,1,2,3} at o=l31
    float* ob = out + (size_t)(bg * D + l31) * N + qbase + 4 * h;
#pragma unroll
    for (int rr = 0; rr < 4; ++rr)
        *reinterpret_cast<float4*>(ob + 8 * rr) =
            make_float4(oc[4 * rr], oc[4 * rr + 1], oc[4 * rr + 2], oc[4 * rr + 3]);
}

extern "C" void kernel_launch(void* const* d_in, const int* in_sizes, int n_in,
                              void* d_out, int out_size, void* d_ws, size_t ws_size,
                              hipStream_t stream) {
    const float* x  = (const float*)d_in[0];
    const float* Wq = (const float*)d_in[1];
    const float* bq = (const float*)d_in[2];
    const float* Wk = (const float*)d_in[3];
    const float* bk = (const float*)d_in[4];
    const float* Wv = (const float*)d_in[5];
    const float* bv = (const float*)d_in[6];
    const float* Wp = (const float*)d_in[7];
    const float* bp = (const float*)d_in[8];
    float* out = (float*)d_out;

    u16* Qb = (u16*)d_ws;                        // [16][4096][32] bf16 = 4 MB
    u16* K2 = Qb + (size_t)NBG * N * D;          // [16][4][4096][8] = 4 MB
    u16* V2 = K2 + (size_t)NBG * N * D;          // [16][512][32][8] = 4 MB

    proj_kernel<<<dim3(N / 256, NBG, 3), 256, 0, stream>>>(x, Wq, bq, Wk, bk, Wv, bv, Qb, K2, V2);
    attn_kernel<<<dim3(NBG * (N / 64)), 256, 0, stream>>>(Qb, K2, V2, Wp, bp, out);
}

// Round 15
// 84.414 us; speedup vs baseline: 1.0756x; 1.0756x over previous
//
#include <hip/hip_runtime.h>
#include <hip/hip_bf16.h>

// SelfAttention b=2, heads=8, D=32, n=4096 (64x64).
// Pass 1 (proj_kernel, z=Q/K/V): x -> Q bf16 [bg][n][32] (pre-scaled by
//   SCALE*log2e), K2 bf16 [bg][dgrp=d/8][key][8], V2 bf16 sigma-ordered
//   [bg][key16grp][h][d][8] -- fragment-native layouts (r13-proven) with
//   V2's key order chosen to equal S^T's in-lane key order, so PV A-frags
//   are the direct cvt_pk of the exp2 outputs (r15: permswaps deleted).
// Pass 2 (attn_kernel): 32x32 MFMA flash attention, 32 q/wave, KVBLK=32,
//   no LDS in loop, no cross-lane ops in loop:
//     S^T = mfma32(K,Q)x2 (col=q=lane&31) -> exp2 x16 -> cvt_pk x8
//     -> PV A-frags direct -> O += mfma32(P,V)x2
//     lsum += mfma32(P,ones)x2 on the matrix pipe (rows match oacc ->
//     lane-local normalize, no shfl; replaces the fp32 add tree).
//   Endgame LDS transpose for the Wp-projection MFMA (r13-proven).
// r14 key-split reverted (occupancy up but total VALU-cycles grew).

constexpr int D = 32;
constexpr int N = 4096;
constexpr int NBG = 16;
constexpr float SCALE = 0.17677669529663687f;   // 32^-0.5
constexpr float LOG2E = 1.4426950408889634f;

using bfrag  = __attribute__((ext_vector_type(8))) short;   // 8 bf16
using s16x8  = __attribute__((ext_vector_type(8))) short;
using f32x16 = __attribute__((ext_vector_type(16))) float;
typedef unsigned short u16;
typedef unsigned int u32;

constexpr int PSTR = 34;            // endgame tile row stride in u16

__device__ __forceinline__ float fexp2(float x) { return __builtin_amdgcn_exp2f(x); }

__device__ __forceinline__ short f2bfs(float f) {
    __hip_bfloat16 h = __float2bfloat16(f);
    return (short)__builtin_bit_cast(u16, h);
}

__device__ __forceinline__ u32 cvt_pk_bf16(float lo, float hi) {
    u32 r;
    asm("v_cvt_pk_bf16_f32 %0, %1, %2" : "=v"(r) : "v"(lo), "v"(hi));
    return r;
}

// ---------------- pass 1: projections -> fragment-native bf16 scratch -----
__global__ __launch_bounds__(256) void proj_kernel(
    const float* __restrict__ x,
    const float* __restrict__ Wq, const float* __restrict__ bq,
    const float* __restrict__ Wk, const float* __restrict__ bk,
    const float* __restrict__ Wv, const float* __restrict__ bv,
    u16* __restrict__ Qb, u16* __restrict__ K2, u16* __restrict__ V2) {
    const int bg = blockIdx.y, g = bg & 7;
    const int z  = blockIdx.z;                       // 0=Q 1=K 2=V
    const int i  = blockIdx.x * 256 + threadIdx.x;   // key / pixel index

    const float* W  = (z == 0) ? Wq : (z == 1) ? Wk : Wv;
    const float* bb = (z == 0) ? bq : (z == 1) ? bk : bv;

    const float* xb = x + (size_t)bg * D * N;
    float xv[D];
#pragma unroll
    for (int d = 0; d < D; ++d) xv[d] = xb[(size_t)d * N + i];

    const float* w = W + g * D * D;
    float acc[D];
#pragma unroll
    for (int o = 0; o < D; ++o) {
        float a0 = 0.f, a1 = 0.f, a2 = 0.f, a3 = 0.f;
#pragma unroll
        for (int d = 0; d < D; d += 4) {
            a0 = fmaf(w[o * D + d    ], xv[d    ], a0);
            a1 = fmaf(w[o * D + d + 1], xv[d + 1], a1);
            a2 = fmaf(w[o * D + d + 2], xv[d + 2], a2);
            a3 = fmaf(w[o * D + d + 3], xv[d + 3], a3);
        }
        acc[o] = (a0 + a1) + (a2 + a3) + bb[g * D + o];
    }

    if (z == 0) {                                    // Q -> row [n][32]
        u16* dst = Qb + ((size_t)bg * N + i) * D;
#pragma unroll
        for (int t = 0; t < 4; ++t) {
            s16x8 v;
#pragma unroll
            for (int e = 0; e < 8; ++e) v[e] = f2bfs(acc[8 * t + e] * (SCALE * LOG2E));
            *reinterpret_cast<s16x8*>(dst + 8 * t) = v;
        }
    } else if (z == 1) {                             // K -> [dgrp][key][8]
        u16* kb2 = K2 + (size_t)bg * N * D;
#pragma unroll
        for (int t = 0; t < 4; ++t) {                // dgrp = t
            s16x8 v;
#pragma unroll
            for (int e = 0; e < 8; ++e) v[e] = f2bfs(acc[8 * t + e]);
            *reinterpret_cast<s16x8*>(kb2 + (size_t)t * N * 8 + (size_t)i * 8) = v;
        }
    } else {
        // V -> sigma-ordered [key16grp][h][d][8]:
        // key j=i&15 sits at h=(j>>2)&1, e=(j&3)+4*((j>>3)&1), matching the
        // S^T in-lane key order (row = (e&3)+8*(e>>2)+4h) -> no permswap.
        const int j  = i & 15;
        const int hh = (j >> 2) & 1;
        const int ee = (j & 3) + 4 * ((j >> 3) & 1);
        u16* vb2 = V2 + (size_t)bg * N * D + (size_t)(i >> 4) * 512 + hh * 256 + ee;
#pragma unroll
        for (int o = 0; o < D; ++o)
            vb2[o * 8] = (u16)f2bfs(acc[o]);
    }
}

// ---------------- pass 2: 32x32 MFMA flash attention, no loop LDS ----------
__global__ __launch_bounds__(256) void attn_kernel(
    const u16* __restrict__ Qb, const u16* __restrict__ K2, const u16* __restrict__ V2,
    const float* __restrict__ Wp, const float* __restrict__ bp,
    float* __restrict__ out) {
    const int s = blockIdx.x;
    const int bg = s & 15, qt = s >> 4, g = bg & 7;   // bg fastest -> XCD L2 reuse
    const int wid = threadIdx.x >> 6;
    const int lane = threadIdx.x & 63;
    const int l31 = lane & 31, h = lane >> 5;
    const int qbase = qt * 128 + wid * 32;            // 32 q rows per wave

    __shared__ u16 plds_all[4][32][PSTR];             // endgame transpose only
    u16* tile = &plds_all[wid][0][0];

    const u16* Qw = Qb + (size_t)bg * N * D;
    const u16* Kw = K2 + (size_t)bg * N * D;
    const u16* Vw = V2 + (size_t)bg * N * D;

    // Q B-fragments (col=q=l31, k-slots d=8h+e), held whole loop
    const u16* qrow = Qw + (size_t)(qbase + l31) * D + 8 * h;
    bfrag qf0 = *reinterpret_cast<const bfrag*>(qrow);
    bfrag qf1 = *reinterpret_cast<const bfrag*>(qrow + 16);

    // Wp B-fragments (col=o=l31, k-slots d=8h+e) + bias
    bfrag wf0, wf1;
    {
        const float* wrow = Wp + (size_t)(g * D + l31) * D + 8 * h;
#pragma unroll
        for (int e = 0; e < 8; ++e) { wf0[e] = f2bfs(wrow[e]); wf1[e] = f2bfs(wrow[16 + e]); }
    }
    const float bias = bp[g * D + l31];

    // ones B-fragment (bf16 1.0) for the lsum MFMA
    bfrag onesf;
#pragma unroll
    for (int e = 0; e < 8; ++e) onesf[e] = (short)0x3F80;

    const f32x16 zf16 = {};          // persistent zero accumulator seed
    f32x16 oacc  = {};
    f32x16 lsacc = {};

    // fragment-native bases: every in-loop load is 1KB contiguous per wave
    const u16* kBase = Kw + (size_t)h * N * 8 + (size_t)l31 * 8;  // dgrp h, key l31
    const u16* vBase = Vw + h * 256 + l31 * 8;                    // h-group, d=l31

    bfrag klo = *reinterpret_cast<const bfrag*>(kBase);                 // d 8h+e,  keys l31
    bfrag khi = *reinterpret_cast<const bfrag*>(kBase + 2 * N * 8);     // d 16+8h+e
    bfrag va  = *reinterpret_cast<const bfrag*>(vBase);                 // keys(sigma) grp0, d=l31
    bfrag vb  = *reinterpret_cast<const bfrag*>(vBase + 512);           // keys(sigma) grp1

    for (int kb = 0; kb < N; kb += 32) {
        bfrag kloc = klo, khic = khi, vac = va, vbc = vb;
        if (kb + 32 < N) {                             // register prefetch
            klo = *reinterpret_cast<const bfrag*>(kBase + (size_t)(kb + 32) * 8);
            khi = *reinterpret_cast<const bfrag*>(kBase + 2 * N * 8 + (size_t)(kb + 32) * 8);
            va  = *reinterpret_cast<const bfrag*>(vBase + (size_t)(kb + 32) * 32);
            vb  = *reinterpret_cast<const bfrag*>(vBase + 512 + (size_t)(kb + 32) * 32);
        }

        // S^T[key][q]: col=q=l31, row=key=(r&3)+8*(r>>2)+4h
        f32x16 sacc = __builtin_amdgcn_mfma_f32_32x32x16_bf16(kloc, qf0, zf16, 0, 0, 0);
        sacc = __builtin_amdgcn_mfma_f32_32x32x16_bf16(khic, qf1, sacc, 0, 0, 0);

        // exp2 (logits bounded; Q pre-scaled by log2e)
        float p[16];
#pragma unroll
        for (int r = 0; r < 16; ++r) p[r] = fexp2(sacc[r]);

        // PV A-frags are the DIRECT pack: V2's sigma order == S^T reg order
        uint4 f1 = make_uint4(cvt_pk_bf16(p[0],  p[1]),  cvt_pk_bf16(p[2],  p[3]),
                              cvt_pk_bf16(p[4],  p[5]),  cvt_pk_bf16(p[6],  p[7]));
        uint4 f2 = make_uint4(cvt_pk_bf16(p[8],  p[9]),  cvt_pk_bf16(p[10], p[11]),
                              cvt_pk_bf16(p[12], p[13]), cvt_pk_bf16(p[14], p[15]));
        const bfrag pf1 = __builtin_bit_cast(bfrag, f1);
        const bfrag pf2 = __builtin_bit_cast(bfrag, f2);

        oacc  = __builtin_amdgcn_mfma_f32_32x32x16_bf16(pf1, vac,   oacc,  0, 0, 0);
        oacc  = __builtin_amdgcn_mfma_f32_32x32x16_bf16(pf2, vbc,   oacc,  0, 0, 0);
        // denominator on the matrix pipe; rows match oacc -> lane-local later
        lsacc = __builtin_amdgcn_mfma_f32_32x32x16_bf16(pf1, onesf, lsacc, 0, 0, 0);
        lsacc = __builtin_amdgcn_mfma_f32_32x32x16_bf16(pf2, onesf, lsacc, 0, 0, 0);
    }

    // normalize rows (reg r of oacc and lsacc both belong to row
    // q=(r&3)+8*(r>>2)+4h) and transpose O via the endgame LDS tile
#pragma unroll
    for (int r = 0; r < 16; ++r) {
        const int q = (r & 3) + 8 * (r >> 2) + 4 * h;
        tile[q * PSTR + l31] = (u16)f2bfs(oacc[r] / lsacc[r]);
    }

    asm volatile("" ::: "memory");   // endgame only: order tile write->read

    // O A-fragments: row=q=l31, k-slots d=8h+e
    bfrag oa0 = *reinterpret_cast<const bfrag*>(tile + l31 * PSTR + 8 * h);
    bfrag oa1 = *reinterpret_cast<const bfrag*>(tile + l31 * PSTR + 16 + 8 * h);

    // OUT[q][o] = O_norm @ Wp^T + bias: col=o=l31, row=q=(r&3)+8*(r>>2)+4h
    f32x16 oc;
#pragma unroll
    for (int r = 0; r < 16; ++r) oc[r] = bias;
    oc = __builtin_amdgcn_mfma_f32_32x32x16_bf16(oa0, wf0, oc, 0, 0, 0);
    oc = __builtin_amdgcn_mfma_f32_32x32x16_bf16(oa1, wf1, oc, 0, 0, 0);

    // store: reg group rr holds q = qbase + 8*rr + 4h + {0,1,2,3} at o=l31
    float* ob = out + (size_t)(bg * D + l31) * N + qbase + 4 * h;
#pragma unroll
    for (int rr = 0; rr < 4; ++rr)
        *reinterpret_cast<float4*>(ob + 8 * rr) =
            make_float4(oc[4 * rr], oc[4 * rr + 1], oc[4 * rr + 2], oc[4 * rr + 3]);
}

extern "C" void kernel_launch(void* const* d_in, const int* in_sizes, int n_in,
                              void* d_out, int out_size, void* d_ws, size_t ws_size,
                              hipStream_t stream) {
    const float* x  = (const float*)d_in[0];
    const float* Wq = (const float*)d_in[1];
    const float* bq = (const float*)d_in[2];
    const float* Wk = (const float*)d_in[3];
    const float* bk = (const float*)d_in[4];
    const float* Wv = (const float*)d_in[5];
    const float* bv = (const float*)d_in[6];
    const float* Wp = (const float*)d_in[7];
    const float* bp = (const float*)d_in[8];
    float* out = (float*)d_out;

    u16* Qb = (u16*)d_ws;                        // [16][4096][32] bf16 = 4 MB
    u16* K2 = Qb + (size_t)NBG * N * D;          // [16][4][4096][8] = 4 MB
    u16* V2 = K2 + (size_t)NBG * N * D;          // [16][256][2][32][8] = 4 MB

    proj_kernel<<<dim3(N / 256, NBG, 3), 256, 0, stream>>>(x, Wq, bq, Wk, bk, Wv, bv, Qb, K2, V2);
    attn_kernel<<<dim3(NBG * (N / 128)), 256, 0, stream>>>(Qb, K2, V2, Wp, bp, out);
}